// Round 17
// baseline (30.796 us; speedup 1.0000x reference)
//
#include <hip/hip_runtime.h>
#include <hip/hip_bf16.h>
#include <stdint.h>

#define N_ROWS 4096
#define D_DIM  256
#define TWO_N  8192
#define C_EXP  2.8853900817779268f       // 2*log2(e): exp(2*dot)=2^(dot*2*log2e)

typedef __attribute__((ext_vector_type(4))) float f32x4;
typedef __attribute__((ext_vector_type(4))) int   int4v;   // 4 VGPR = 32 fp4 elems
typedef __attribute__((ext_vector_type(8))) int   int8v;

// Packed fp4 fragment-native layout (16x16x128 f8f6f4 FP4 operand, 1024 B frags):
//   row r, k:  frag = (r>>4)*2 + (k>>7)
//   lane slot = ((k>>5)&3)*16 + (r&15)          [16 B per lane]
//   nibble    = k&31  (byte (k&31)>>1, low nibble first)
// kmain loads one frag as *(int4v*)(packed + frag*1024 + lane*16).
// Any consistent within-block k/nibble permutation cancels between A and B.

// e2m1 quantizer on the x16 grid: values {0,.5,1,1.5,2,3,4,6}, returns reconstruction
__device__ __forceinline__ float q4(float c, unsigned& code) {
    float x = c * 16.0f;
    unsigned s = __float_as_uint(x) >> 31;
    float ax = fminf(fabsf(x), 6.0f);
    unsigned q; float v;
    if (ax < 2.0f)      { float r = rintf(ax * 2.0f); q = (unsigned)r;      v = r * 0.5f; }
    else if (ax < 4.0f) { float r = rintf(ax);        q = (unsigned)r + 2u; v = r;        }
    else                { float r = rintf(ax * 0.5f); q = (unsigned)r + 4u; v = r * 2.0f; }
    code = q | (s << 3);
    return s ? -v : v;     // value on the x16 grid (true component = v/16)
}

// ---------- K1: normalize -> packed fp4 frags, exact pos sims, fp4 self-dot exp, zero accum ----------
__global__ __launch_bounds__(256) void kprep(const float* __restrict__ zi,
                                             const float* __restrict__ zj,
                                             char* __restrict__ packed,
                                             float* __restrict__ pos,
                                             float* __restrict__ selfexp,
                                             float* __restrict__ rowsum,
                                             float* __restrict__ out) {
    int wave = threadIdx.x >> 6, lane = threadIdx.x & 63;
    int k = blockIdx.x * 4 + wave;   // 0..4095
    float4 a = *(const float4*)(zi + (size_t)k * D_DIM + lane * 4);
    float4 b = *(const float4*)(zj + (size_t)k * D_DIM + lane * 4);
    float dii = a.x * a.x + a.y * a.y + a.z * a.z + a.w * a.w;
    float djj = b.x * b.x + b.y * b.y + b.z * b.z + b.w * b.w;
    float dij = a.x * b.x + a.y * b.y + a.z * b.z + a.w * b.w;
#pragma unroll
    for (int m = 1; m < 64; m <<= 1) {
        dii += __shfl_xor(dii, m, 64);
        djj += __shfl_xor(djj, m, 64);
        dij += __shfl_xor(dij, m, 64);
    }
    float si = 1.0f / fmaxf(sqrtf(dii), 1e-12f);
    float sj = 1.0f / fmaxf(sqrtf(djj), 1e-12f);

    // quantize 4 components of each row to fp4 (x16 grid), pack 4 nibbles -> u16
    unsigned c0, c1, c2, c3;
    float va0 = q4(a.x * si, c0), va1 = q4(a.y * si, c1);
    float va2 = q4(a.z * si, c2), va3 = q4(a.w * si, c3);
    unsigned na = c0 | (c1 << 4) | (c2 << 8) | (c3 << 12);
    float vb0 = q4(b.x * sj, c0), vb1 = q4(b.y * sj, c1);
    float vb2 = q4(b.z * sj, c2), vb3 = q4(b.w * sj, c3);
    unsigned nb = c0 | (c1 << 4) | (c2 << 8) | (c3 << 12);

    // scatter: k0 = 4*lane -> frag-half f, 32k-group g, byte offset within 16B slot
    const int f = lane >> 5;
    const int g = (lane >> 3) & 3;
    const int off2 = 2 * (lane & 7);
    {
        int r = k;
        int byte = ((r >> 4) * 2 + f) * 1024 + (g * 16 + (r & 15)) * 16 + off2;
        *(unsigned short*)(packed + byte) = (unsigned short)na;
    }
    {
        int r = k + N_ROWS;
        int byte = ((r >> 4) * 2 + f) * 1024 + (g * 16 + (r & 15)) * 16 + off2;
        *(unsigned short*)(packed + byte) = (unsigned short)nb;
    }

    // self-dot of the fp4-ROUNDED vectors (x16 grid -> /256)
    float sa = va0 * va0 + va1 * va1 + va2 * va2 + va3 * va3;
    float sb = vb0 * vb0 + vb1 * vb1 + vb2 * vb2 + vb3 * vb3;
#pragma unroll
    for (int m = 1; m < 64; m <<= 1) {
        sa += __shfl_xor(sa, m, 64);
        sb += __shfl_xor(sb, m, 64);
    }
    if (lane == 0) {
        float p = dij * si * sj * 2.0f;   // /TEMPERATURE (exact f32)
        pos[k] = p;
        pos[k + N_ROWS] = p;
        selfexp[k] = __builtin_amdgcn_exp2f(sa * (C_EXP / 256.0f));
        selfexp[k + N_ROWS] = __builtin_amdgcn_exp2f(sb * (C_EXP / 256.0f));
    }
    if (threadIdx.x < 8) rowsum[blockIdx.x * 8 + threadIdx.x] = 0.0f;
    if (blockIdx.x == 0 && threadIdx.x == 0) out[0] = 0.0f;   // kfinal accumulates
}

// ---------- K2: barrier-free fp4 MX main loop, 2x2 wave grid ----------
// 1056 blocks (R13 decode, validated). Waves split rows AND cols: wave (wr,wc) owns
// 64 rows x 64 cols of each 128x128 tile -> per-tile B-frag traffic halves vs R16
// (each wave loads only its 64-col half; A loaded once per block). Per tile per wave:
// 8 B-frag loads (16B/lane) + 32 mfma_scale 16x16x128 FP4. No LDS staging, no
// main-loop barriers. Col-partials in wave-private LDS; one barrier before flush.
__global__ __launch_bounds__(256) void kmain(const char* __restrict__ packed,
                                             float* __restrict__ rowsum) {
    __shared__ float colpart[4][256];

    const int tid = threadIdx.x;
    const int wave = tid >> 6, lane = tid & 63;
    const int l15 = lane & 15, lhi = lane >> 4;
    const int wr = wave >> 1, wc = wave & 1;

    // bijective XCD swizzle (1056 = 8*132) + block decode  (R13 verbatim)
    int b = (blockIdx.x & 7) * 132 + (blockIdx.x >> 3);
    int rt, s0, nt;
    if (b < 1024) { rt = b >> 4; s0 = (b & 15) * 2; nt = 2; }
    else          { rt = b - 1024; s0 = 32; nt = 1; }

#pragma unroll
    for (int i = 0; i < 4; ++i) colpart[wave][i * 64 + lane] = 0.0f;

    // A fragments: 4 row-frags (16 rows) x 2 k-frags (K=128), 16B/lane each
    const int rtile = rt * 8 + wr * 4;
    int4v afrag[4][2];
#pragma unroll
    for (int rf = 0; rf < 4; ++rf)
#pragma unroll
        for (int f = 0; f < 2; ++f)
            afrag[rf][f] = *(const int4v*)(packed + (size_t)((rtile + rf) * 2 + f) * 1024 + lane * 16);

    float rsum[4][4];
#pragma unroll
    for (int rf = 0; rf < 4; ++rf)
#pragma unroll
        for (int r = 0; r < 4; ++r) rsum[rf][r] = 0.0f;

    for (int ti = 0; ti < nt; ++ti) {
        const int ct = (rt + s0 + ti) & 63;
        const int ctile = ct * 8 + wc * 4;     // this wave's 64-col half

        f32x4 acc[4][4];
#pragma unroll
        for (int rf = 0; rf < 4; ++rf)
#pragma unroll
            for (int cf = 0; cf < 4; ++cf) acc[rf][cf] = (f32x4){0.f, 0.f, 0.f, 0.f};

#pragma unroll
        for (int f = 0; f < 2; ++f) {
            int4v bfr[4];
#pragma unroll
            for (int cf = 0; cf < 4; ++cf)
                bfr[cf] = *(const int4v*)(packed + (size_t)((ctile + cf) * 2 + f) * 1024 + lane * 16);
#pragma unroll
            for (int rf = 0; rf < 4; ++rf) {
                int8v A8 = {afrag[rf][f][0], afrag[rf][f][1], afrag[rf][f][2], afrag[rf][f][3], 0, 0, 0, 0};
#pragma unroll
                for (int cf = 0; cf < 4; ++cf) {
                    int8v B8 = {bfr[cf][0], bfr[cf][1], bfr[cf][2], bfr[cf][3], 0, 0, 0, 0};
                    acc[rf][cf] = __builtin_amdgcn_mfma_scale_f32_16x16x128_f8f6f4(
                        A8, B8, acc[rf][cf],
                        4, 4,                      // cbsz=FP4, blgp=FP4
                        0, 0x7B7B7B7B,             // A scale: E8M0 123 = 2^-4
                        0, 0x7B7B7B7B);            // B scale: E8M0 123 = 2^-4
                }
            }
        }

        // epilogue: exp once -> row-partials (regs) + col-partials (wave-private LDS)
#pragma unroll
        for (int cf = 0; cf < 4; ++cf) {
            float cacc = 0.0f;
#pragma unroll
            for (int rf = 0; rf < 4; ++rf) {
                f32x4 cv = acc[rf][cf];
#pragma unroll
                for (int r = 0; r < 4; ++r) {
                    float e = __builtin_amdgcn_exp2f(cv[r] * C_EXP);
                    rsum[rf][r] += e;
                    cacc += e;
                }
            }
            cacc += __shfl_xor(cacc, 16, 64);
            cacc += __shfl_xor(cacc, 32, 64);
            if (lane < 16)
                colpart[wave][ti * 128 + wc * 64 + cf * 16 + lane] += cacc;
        }
    }

    // batched col-flush (symmetry): one barrier, one atomic per col  (R13 verbatim)
    __syncthreads();
    {
        int ti = tid >> 7;
        int c  = tid & 127;
        int s  = s0 + ti;
        if (ti < nt && s > 0) {
            int ct = (rt + s) & 63;
            atomicAdd(&rowsum[ct * 128 + c],
                      colpart[0][tid] + colpart[1][tid] +
                      colpart[2][tid] + colpart[3][tid]);
        }
    }

    // row-partials: one atomic per row
#pragma unroll
    for (int rf = 0; rf < 4; ++rf)
#pragma unroll
        for (int r = 0; r < 4; ++r) {
            float v = rsum[rf][r];
            v += __shfl_xor(v, 1, 64);
            v += __shfl_xor(v, 2, 64);
            v += __shfl_xor(v, 4, 64);
            v += __shfl_xor(v, 8, 64);
            if (l15 == 0)
                atomicAdd(&rowsum[rt * 128 + wr * 64 + rf * 16 + lhi * 4 + r], v);
        }
}

// ---------- K3: parallel loss reduce — 32 blocks, block partials atomicAdd into out ----------
__global__ __launch_bounds__(256) void kfinal(const float* __restrict__ rowsum,
                                              const float* __restrict__ pos,
                                              const float* __restrict__ selfexp,
                                              float* __restrict__ out) {
    __shared__ float red[4];
    int r = blockIdx.x * 256 + threadIdx.x;   // 0..8191
    float local = __builtin_amdgcn_logf(rowsum[r] - selfexp[r]) * 0.6931471805599453f - pos[r];
#pragma unroll
    for (int m = 1; m < 64; m <<= 1) local += __shfl_xor(local, m, 64);
    if ((threadIdx.x & 63) == 0) red[threadIdx.x >> 6] = local;
    __syncthreads();
    if (threadIdx.x == 0)
        atomicAdd(out, (red[0] + red[1] + red[2] + red[3]) * (1.0f / (float)TWO_N));
}

extern "C" void kernel_launch(void* const* d_in, const int* in_sizes, int n_in,
                              void* d_out, int out_size, void* d_ws, size_t ws_size,
                              hipStream_t stream) {
    const float* zi = (const float*)d_in[0];
    const float* zj = (const float*)d_in[1];
    float* out = (float*)d_out;

    char* packed = (char*)d_ws;                                          // 1 MiB (fp4)
    float* rowsum = (float*)((char*)d_ws + (size_t)TWO_N * D_DIM * 2);   // at 4 MiB mark
    float* pos = rowsum + TWO_N;
    float* selfexp = pos + TWO_N;

    kprep<<<1024, 256, 0, stream>>>(zi, zj, packed, pos, selfexp, rowsum, out);
    kmain<<<1056, 256, 0, stream>>>(packed, rowsum);
    kfinal<<<32, 256, 0, stream>>>(rowsum, pos, selfexp, out);
}

// Round 18
// 27.817 us; speedup vs baseline: 1.1071x; 1.1071x over previous
//
#include <hip/hip_runtime.h>
#include <hip/hip_bf16.h>
#include <stdint.h>

#define N_ROWS 4096
#define D_DIM  256
#define TWO_N  8192
#define C_EXP  2.8853900817779268f       // 2*log2(e): exp(2*dot)=2^(dot*2*log2e)

typedef __attribute__((ext_vector_type(4))) float f32x4;
typedef __attribute__((ext_vector_type(4))) int   int4v;   // 4 VGPR = 32 fp4 elems
typedef __attribute__((ext_vector_type(8))) int   int8v;

// Packed fp4 fragment-native layout (16x16x128 f8f6f4 FP4 operand, 1024 B frags):
//   row r, k:  frag = (r>>4)*2 + (k>>7)
//   lane slot = ((k>>5)&3)*16 + (r&15)          [16 B per lane]
//   nibble    = k&31  (byte (k&31)>>1, low nibble first)
// kmain loads one frag as *(int4v*)(packed + frag*1024 + lane*16).
// Any consistent within-block k/nibble permutation cancels between A and B.

// e2m1 quantizer on the x16 grid: values {0,.5,1,1.5,2,3,4,6}, returns reconstruction
__device__ __forceinline__ float q4(float c, unsigned& code) {
    float x = c * 16.0f;
    unsigned s = __float_as_uint(x) >> 31;
    float ax = fminf(fabsf(x), 6.0f);
    unsigned q; float v;
    if (ax < 2.0f)      { float r = rintf(ax * 2.0f); q = (unsigned)r;      v = r * 0.5f; }
    else if (ax < 4.0f) { float r = rintf(ax);        q = (unsigned)r + 2u; v = r;        }
    else                { float r = rintf(ax * 0.5f); q = (unsigned)r + 4u; v = r * 2.0f; }
    code = q | (s << 3);
    return s ? -v : v;     // value on the x16 grid (true component = v/16)
}

// ---------- K1: normalize -> packed fp4 frags, exact pos sims, fp4 self-dot exp, zero accum ----------
__global__ __launch_bounds__(256) void kprep(const float* __restrict__ zi,
                                             const float* __restrict__ zj,
                                             char* __restrict__ packed,
                                             float* __restrict__ pos,
                                             float* __restrict__ selfexp,
                                             float* __restrict__ rowsum,
                                             float* __restrict__ out) {
    int wave = threadIdx.x >> 6, lane = threadIdx.x & 63;
    int k = blockIdx.x * 4 + wave;   // 0..4095
    float4 a = *(const float4*)(zi + (size_t)k * D_DIM + lane * 4);
    float4 b = *(const float4*)(zj + (size_t)k * D_DIM + lane * 4);
    float dii = a.x * a.x + a.y * a.y + a.z * a.z + a.w * a.w;
    float djj = b.x * b.x + b.y * b.y + b.z * b.z + b.w * b.w;
    float dij = a.x * b.x + a.y * b.y + a.z * b.z + a.w * b.w;
#pragma unroll
    for (int m = 1; m < 64; m <<= 1) {
        dii += __shfl_xor(dii, m, 64);
        djj += __shfl_xor(djj, m, 64);
        dij += __shfl_xor(dij, m, 64);
    }
    float si = 1.0f / fmaxf(sqrtf(dii), 1e-12f);
    float sj = 1.0f / fmaxf(sqrtf(djj), 1e-12f);

    // quantize 4 components of each row to fp4 (x16 grid), pack 4 nibbles -> u16
    unsigned c0, c1, c2, c3;
    float va0 = q4(a.x * si, c0), va1 = q4(a.y * si, c1);
    float va2 = q4(a.z * si, c2), va3 = q4(a.w * si, c3);
    unsigned na = c0 | (c1 << 4) | (c2 << 8) | (c3 << 12);
    float vb0 = q4(b.x * sj, c0), vb1 = q4(b.y * sj, c1);
    float vb2 = q4(b.z * sj, c2), vb3 = q4(b.w * sj, c3);
    unsigned nb = c0 | (c1 << 4) | (c2 << 8) | (c3 << 12);

    // scatter: k0 = 4*lane -> frag-half f, 32k-group g, byte offset within 16B slot
    const int f = lane >> 5;
    const int g = (lane >> 3) & 3;
    const int off2 = 2 * (lane & 7);
    {
        int r = k;
        int byte = ((r >> 4) * 2 + f) * 1024 + (g * 16 + (r & 15)) * 16 + off2;
        *(unsigned short*)(packed + byte) = (unsigned short)na;
    }
    {
        int r = k + N_ROWS;
        int byte = ((r >> 4) * 2 + f) * 1024 + (g * 16 + (r & 15)) * 16 + off2;
        *(unsigned short*)(packed + byte) = (unsigned short)nb;
    }

    // self-dot of the fp4-ROUNDED vectors (x16 grid -> /256)
    float sa = va0 * va0 + va1 * va1 + va2 * va2 + va3 * va3;
    float sb = vb0 * vb0 + vb1 * vb1 + vb2 * vb2 + vb3 * vb3;
#pragma unroll
    for (int m = 1; m < 64; m <<= 1) {
        sa += __shfl_xor(sa, m, 64);
        sb += __shfl_xor(sb, m, 64);
    }
    if (lane == 0) {
        float p = dij * si * sj * 2.0f;   // /TEMPERATURE (exact f32)
        pos[k] = p;
        pos[k + N_ROWS] = p;
        selfexp[k] = __builtin_amdgcn_exp2f(sa * (C_EXP / 256.0f));
        selfexp[k + N_ROWS] = __builtin_amdgcn_exp2f(sb * (C_EXP / 256.0f));
    }
    if (threadIdx.x < 8) rowsum[blockIdx.x * 8 + threadIdx.x] = 0.0f;
    if (blockIdx.x == 0 && threadIdx.x == 0) out[0] = 0.0f;   // kfinal accumulates
}

// ---------- K2: barrier-free fp4 MX main loop — frags straight from L1/L2 ----------
// 1056 blocks (R13 decode, validated). Per sub-tile: 16 mfma_scale 16x16x128 FP4
// (cbsz=blgp=4), scale bytes 0x7B = 2^-4 per operand -> product /256. 8 B-loads of
// 16B/lane. No LDS staging, no main-loop barriers. Col-partials in wave-private LDS;
// one barrier before batched flush. (R16 config: 4x1 waves, ~100 VGPR, 5 waves/SIMD —
// latency-bound kernel, occupancy beats traffic reduction; R17's 2x2 grid regressed.)
__global__ __launch_bounds__(256) void kmain(const char* __restrict__ packed,
                                             float* __restrict__ rowsum) {
    __shared__ float colpart[4][256];

    const int tid = threadIdx.x;
    const int wave = tid >> 6, lane = tid & 63;
    const int l15 = lane & 15, lhi = lane >> 4;

    // bijective XCD swizzle (1056 = 8*132) + block decode  (R13 verbatim)
    int b = (blockIdx.x & 7) * 132 + (blockIdx.x >> 3);
    int rt, s0, nt;
    if (b < 1024) { rt = b >> 4; s0 = (b & 15) * 2; nt = 2; }
    else          { rt = b - 1024; s0 = 32; nt = 1; }

    const int rowbaseW = rt * 128 + wave * 32;

#pragma unroll
    for (int i = 0; i < 4; ++i) colpart[wave][i * 64 + lane] = 0.0f;

    // A fragments: 2 row-frags (16 rows) x 2 k-frags (K=128), 16B/lane each
    const int rtile = rt * 8 + wave * 2;
    int4v afrag[2][2];
#pragma unroll
    for (int rf = 0; rf < 2; ++rf)
#pragma unroll
        for (int f = 0; f < 2; ++f)
            afrag[rf][f] = *(const int4v*)(packed + (size_t)((rtile + rf) * 2 + f) * 1024 + lane * 16);

    float rsum[2][4];
#pragma unroll
    for (int rf = 0; rf < 2; ++rf)
#pragma unroll
        for (int r = 0; r < 4; ++r) rsum[rf][r] = 0.0f;

    for (int ti = 0; ti < nt; ++ti) {
        const int ct = (rt + s0 + ti) & 63;

#pragma unroll
        for (int sub = 0; sub < 2; ++sub) {
            const int ctile = ct * 8 + sub * 4;

            f32x4 acc[2][4];
#pragma unroll
            for (int rf = 0; rf < 2; ++rf)
#pragma unroll
                for (int cf = 0; cf < 4; ++cf) acc[rf][cf] = (f32x4){0.f, 0.f, 0.f, 0.f};

#pragma unroll
            for (int f = 0; f < 2; ++f) {
                int4v bfr[4];
#pragma unroll
                for (int cf = 0; cf < 4; ++cf)
                    bfr[cf] = *(const int4v*)(packed + (size_t)((ctile + cf) * 2 + f) * 1024 + lane * 16);
#pragma unroll
                for (int rf = 0; rf < 2; ++rf) {
                    int8v A8 = {afrag[rf][f][0], afrag[rf][f][1], afrag[rf][f][2], afrag[rf][f][3], 0, 0, 0, 0};
#pragma unroll
                    for (int cf = 0; cf < 4; ++cf) {
                        int8v B8 = {bfr[cf][0], bfr[cf][1], bfr[cf][2], bfr[cf][3], 0, 0, 0, 0};
                        acc[rf][cf] = __builtin_amdgcn_mfma_scale_f32_16x16x128_f8f6f4(
                            A8, B8, acc[rf][cf],
                            4, 4,                      // cbsz=FP4, blgp=FP4
                            0, 0x7B7B7B7B,             // A scale: E8M0 123 = 2^-4
                            0, 0x7B7B7B7B);            // B scale: E8M0 123 = 2^-4
                    }
                }
            }

            // epilogue: exp once -> row-partials (regs) + col-partials (wave-private LDS)
#pragma unroll
            for (int cf = 0; cf < 4; ++cf) {
                float cacc = 0.0f;
#pragma unroll
                for (int rf = 0; rf < 2; ++rf) {
                    f32x4 cv = acc[rf][cf];
#pragma unroll
                    for (int r = 0; r < 4; ++r) {
                        float e = __builtin_amdgcn_exp2f(cv[r] * C_EXP);
                        rsum[rf][r] += e;
                        cacc += e;
                    }
                }
                cacc += __shfl_xor(cacc, 16, 64);
                cacc += __shfl_xor(cacc, 32, 64);
                if (lane < 16)
                    colpart[wave][ti * 128 + sub * 64 + cf * 16 + lane] += cacc;
            }
        }
    }

    // batched col-flush (symmetry): one barrier, one atomic per col  (R13 verbatim)
    __syncthreads();
    {
        int ti = tid >> 7;
        int c  = tid & 127;
        int s  = s0 + ti;
        if (ti < nt && s > 0) {
            int ct = (rt + s) & 63;
            atomicAdd(&rowsum[ct * 128 + c],
                      colpart[0][tid] + colpart[1][tid] +
                      colpart[2][tid] + colpart[3][tid]);
        }
    }

    // row-partials: one atomic per row  (R10 verbatim)
#pragma unroll
    for (int rf = 0; rf < 2; ++rf)
#pragma unroll
        for (int r = 0; r < 4; ++r) {
            float v = rsum[rf][r];
            v += __shfl_xor(v, 1, 64);
            v += __shfl_xor(v, 2, 64);
            v += __shfl_xor(v, 4, 64);
            v += __shfl_xor(v, 8, 64);
            if (l15 == 0)
                atomicAdd(&rowsum[rowbaseW + rf * 16 + lhi * 4 + r], v);
        }
}

// ---------- K3: parallel loss reduce — 32 blocks, block partials atomicAdd into out ----------
__global__ __launch_bounds__(256) void kfinal(const float* __restrict__ rowsum,
                                              const float* __restrict__ pos,
                                              const float* __restrict__ selfexp,
                                              float* __restrict__ out) {
    __shared__ float red[4];
    int r = blockIdx.x * 256 + threadIdx.x;   // 0..8191
    float local = __builtin_amdgcn_logf(rowsum[r] - selfexp[r]) * 0.6931471805599453f - pos[r];
#pragma unroll
    for (int m = 1; m < 64; m <<= 1) local += __shfl_xor(local, m, 64);
    if ((threadIdx.x & 63) == 0) red[threadIdx.x >> 6] = local;
    __syncthreads();
    if (threadIdx.x == 0)
        atomicAdd(out, (red[0] + red[1] + red[2] + red[3]) * (1.0f / (float)TWO_N));
}

extern "C" void kernel_launch(void* const* d_in, const int* in_sizes, int n_in,
                              void* d_out, int out_size, void* d_ws, size_t ws_size,
                              hipStream_t stream) {
    const float* zi = (const float*)d_in[0];
    const float* zj = (const float*)d_in[1];
    float* out = (float*)d_out;

    char* packed = (char*)d_ws;                                          // 1 MiB (fp4)
    float* rowsum = (float*)((char*)d_ws + (size_t)TWO_N * D_DIM * 2);   // at 4 MiB mark
    float* pos = rowsum + TWO_N;
    float* selfexp = pos + TWO_N;

    kprep<<<1024, 256, 0, stream>>>(zi, zj, packed, pos, selfexp, rowsum, out);
    kmain<<<1056, 256, 0, stream>>>(packed, rowsum);
    kfinal<<<32, 256, 0, stream>>>(rowsum, pos, selfexp, out);
}